// Round 19
// baseline (565.009 us; speedup 1.0000x reference)
//
#include <hip/hip_runtime.h>

#define E_EDGES 1600000
#define N_NODES_ 100000

typedef unsigned short u16;
typedef unsigned int u32;
typedef short bf16x8 __attribute__((ext_vector_type(8)));
typedef u16 u16x4 __attribute__((ext_vector_type(4)));
typedef float f32x4 __attribute__((ext_vector_type(4)));

#define BAR() do{ asm volatile("s_waitcnt lgkmcnt(0)" ::: "memory"); \
                  __builtin_amdgcn_s_barrier(); }while(0)

__device__ __forceinline__ u16 f2bf(float f){
  u32 u = __builtin_bit_cast(u32, f);
  u += 0x7fffu + ((u >> 16) & 1u);   // round-to-nearest-even
  return (u16)(u >> 16);
}

// Pack 4 (128x128) f32 row-major weight matrices into bf16 fragment order.
// frag (n,kc): lane l holds w[kc*32 + (l>>4)*8 + j][n*16 + (l&15)], j=0..7.
__global__ void pack4(const float* __restrict__ a, const float* __restrict__ b,
                      const float* __restrict__ c, const float* __restrict__ d,
                      u16* __restrict__ pa, u16* __restrict__ pb,
                      u16* __restrict__ pc, u16* __restrict__ pd){
  int tid = blockIdx.x * 256 + threadIdx.x;   // 0..8191
  int mat = tid >> 11, rem = tid & 2047;
  int n = rem >> 8, k = (rem >> 6) & 3, lane = rem & 63;
  const float* w = mat==0 ? a : mat==1 ? b : mat==2 ? c : d;
  u16* p       = mat==0 ? pa : mat==1 ? pb : mat==2 ? pc : pd;
  int rbase = k*32 + (lane>>4)*8;
  int col   = n*16 + (lane&15);
  int o = ((n*4 + k)*64 + lane)*8;
  #pragma unroll
  for (int j=0;j<8;++j) p[o+j] = f2bf(w[(rbase+j)*128 + col]);
}

// Pack xyz (first 3 floats of each 25-float x row) into an L2-friendly float4 table.
__global__ void pack_xyz(const float* __restrict__ x, float4* __restrict__ xyz, int n){
  int i = blockIdx.x * 256 + threadIdx.x;
  if (i < n){
    const float* p = x + (long)i*25;
    float4 v; v.x = p[0]; v.y = p[1]; v.z = p[2]; v.w = 0.f;
    xyz[i] = v;
  }
}

// ============================================================================
// EDGE kernel, wave-independent (R17-proven): each wave owns a 16-edge subtile
// end-to-end, zero barriers in the main loop. R19 = R18 with the nt-store type
// fixed (ext-vector f32x4, not HIP float4 class). NON-TEMPORAL output stores:
// write stream no longer allocates in L2 -> xyz table stays L2-resident for
// the random gather. nt is safe here: every store instruction writes sixteen
// complete 64B sectors (fillBuffer-style), unlike R3's gap-y fragment stores.
// ============================================================================
__global__ __launch_bounds__(1024, 4)
void edge_kernel(const int* __restrict__ eidx, const float4* __restrict__ xyz,
                 const float* __restrict__ w1, const float* __restrict__ b1,
                 const u16* __restrict__ pw2, const float* __restrict__ b2,
                 const u16* __restrict__ pw3, const float* __restrict__ b3,
                 const float* __restrict__ gw, const float* __restrict__ bw,
                 float* __restrict__ out, long outbase)
{
  __shared__ __align__(16) u16 W2L[16384];            // 32KB fragment bytes
  __shared__ __align__(16) u16 W3L[16384];            // 32KB
  __shared__ __align__(16) float w1s[4*132];          // [k][132] padded row-major
  __shared__ __align__(16) float b1L[128];
  __shared__ __align__(16) unsigned char h2buf[16*4096]; // 4KB per wave

  const int tid  = threadIdx.x;
  const int lane = tid & 63, wave = tid >> 6;
  const int li = lane & 15, lg = lane >> 4;
  unsigned char* h2 = h2buf + wave*4096;

  // ---- one-time staging (only block-wide barrier in the kernel) ----
  for (int i = tid; i < 2048; i += 1024){
    ((float4*)W2L)[i] = ((const float4*)pw2)[i];
    ((float4*)W3L)[i] = ((const float4*)pw3)[i];
  }
  for (int i = tid; i < 512; i += 1024){
    int k = i >> 7, f = i & 127;
    w1s[k*132 + f] = w1[i];
  }
  if (tid < 128) b1L[tid] = b1[tid];
  __syncthreads();

  // ---- per-lane constant epilogue params (feature set li + n*16) ----
  float b2v[8], b3v[8], gv[8], bv[8];
  #pragma unroll
  for (int n=0;n<8;++n){
    int f = li + n*16;
    b2v[n] = b2[f]; b3v[n] = b3[f]; gv[n] = gw[f]; bv[n] = bw[f];
  }

  const int NSUB = E_EDGES/16;           // 100000
  const int wid = blockIdx.x*16 + wave;
  const int stride = gridDim.x*16;
  const f32x4 zv = {0.f,0.f,0.f,0.f};

  // prefetch subtile wid (lane handles row li; lg groups redundant -> TA merges)
  float4 pr = {0,0,0,0}, pc = {0,0,0,0};
  if (wid < NSUB){
    long e = (long)wid*16 + li;
    int ir = __builtin_nontemporal_load(eidx + e);
    int ic = __builtin_nontemporal_load(eidx + E_EDGES + e);
    pr = xyz[ir]; pc = xyz[ic];
  }

  for (int s = wid; s < NSUB; s += stride){
    // ---- finish gather math for current subtile ----
    float dx = pr.x-pc.x, dy = pr.y-pc.y, dz = pr.z-pc.z;
    float4 in4; in4.x = dx; in4.y = dy; in4.z = dz;
    in4.w = sqrtf(dx*dx + dy*dy + dz*dz);

    // ---- issue next subtile's gather (overlaps all compute below) ----
    int sn = s + stride;
    if (sn < NSUB){
      long e = (long)sn*16 + li;
      int ir = __builtin_nontemporal_load(eidx + e);
      int ic = __builtin_nontemporal_load(eidx + E_EDGES + e);
      pr = xyz[ir]; pc = xyz[ic];
    }

    // ---- layer 1 -> A-fragments directly (row li, k-chunk lg*8 + kc*32) ----
    bf16x8 af[4];
    #pragma unroll
    for (int kc=0;kc<4;++kc){
      const int f0 = kc*32 + lg*8;
      f32x4 bA = *(const f32x4*)(b1L + f0);
      f32x4 bB = *(const f32x4*)(b1L + f0 + 4);
      float h[8];
      #pragma unroll
      for (int j=0;j<4;++j){ h[j] = bA[j]; h[4+j] = bB[j]; }
      #pragma unroll
      for (int k=0;k<4;++k){
        float xv = (k==0)?in4.x:(k==1)?in4.y:(k==2)?in4.z:in4.w;
        f32x4 wa = *(const f32x4*)(w1s + k*132 + f0);
        f32x4 wb = *(const f32x4*)(w1s + k*132 + f0 + 4);
        #pragma unroll
        for (int j=0;j<4;++j){
          h[j]   = fmaf(xv, wa[j], h[j]);
          h[4+j] = fmaf(xv, wb[j], h[4+j]);
        }
      }
      #pragma unroll
      for (int j=0;j<8;++j){
        float v = h[j] > 0.f ? h[j] : 0.f;
        af[kc][j] = (short)f2bf(v);
      }
    }

    // ---- layer 2: acc[n] = h1 x W2 (B-frags from LDS) ----
    f32x4 acc[8];
    #pragma unroll
    for (int n=0;n<8;++n) acc[n] = zv;
    #pragma unroll
    for (int n=0;n<8;++n)
      #pragma unroll
      for (int kc=0;kc<4;++kc){
        bf16x8 bf = *(const bf16x8*)(W2L + ((n*4+kc)*64 + lane)*8);
        acc[n] = __builtin_amdgcn_mfma_f32_16x16x32_bf16(af[kc], bf, acc[n], 0,0,0);
      }

    // ---- h2 = relu(acc+b2) -> per-wave LDS (R12-proven swizzle bijection) ----
    #pragma unroll
    for (int n=0;n<8;++n){
      #pragma unroll
      for (int j=0;j<4;++j){
        float v = acc[n][j] + b2v[n];
        v = v > 0.f ? v : 0.f;
        const int rr = lg*4 + j;
        const int f  = li + n*16;
        *(u16*)(h2 + rr*256 + ((((f>>3)) ^ (rr&7))<<4) + ((f&7)<<1)) = f2bf(v);
      }
    }
    // wave-local fence: all ds_writes retired before the a2 ds_reads
    asm volatile("s_waitcnt lgkmcnt(0)" ::: "memory");
    __builtin_amdgcn_sched_barrier(0);

    // ---- layer 3: A-frags from h2, B-frags from W3L ----
    bf16x8 a2[4];
    #pragma unroll
    for (int kc=0;kc<4;++kc)
      a2[kc] = *(const bf16x8*)(h2 + li*256 + (((kc*4+lg) ^ (li&7))<<4));
    #pragma unroll
    for (int n=0;n<8;++n) acc[n] = zv;
    #pragma unroll
    for (int n=0;n<8;++n)
      #pragma unroll
      for (int kc=0;kc<4;++kc){
        bf16x8 bf = *(const bf16x8*)(W3L + ((n*4+kc)*64 + lane)*8);
        acc[n] = __builtin_amdgcn_mfma_f32_16x16x32_bf16(a2[kc], bf, acc[n], 0,0,0);
      }

    // ---- LayerNorm fully in registers ----
    float sj[4] = {0,0,0,0}, qj[4] = {0,0,0,0};
    #pragma unroll
    for (int n=0;n<8;++n)
      #pragma unroll
      for (int j=0;j<4;++j){
        float v = acc[n][j] + b3v[n];
        acc[n][j] = v;
        sj[j] += v; qj[j] += v*v;
      }
    #pragma unroll
    for (int j=0;j<4;++j){
      sj[j] += __shfl_xor(sj[j],1);  qj[j] += __shfl_xor(qj[j],1);
      sj[j] += __shfl_xor(sj[j],2);  qj[j] += __shfl_xor(qj[j],2);
      sj[j] += __shfl_xor(sj[j],4);  qj[j] += __shfl_xor(qj[j],4);
      sj[j] += __shfl_xor(sj[j],8);  qj[j] += __shfl_xor(qj[j],8);
    }
    float mu[4], rs[4];
    #pragma unroll
    for (int j=0;j<4;++j){
      mu[j] = sj[j] * 0.0078125f;
      rs[j] = rsqrtf(qj[j]*0.0078125f - mu[j]*mu[j] + 1e-5f);
    }
    #pragma unroll
    for (int n=0;n<8;++n)
      #pragma unroll
      for (int j=0;j<4;++j)
        acc[n][j] = (acc[n][j]-mu[j])*rs[j]*gv[n] + bv[n];

    // ---- 4x4 butterfly transpose (R17-verified selectors) + NT stores ----
    const int t = li & 3;
    const long rowb = outbase + (long)(s*16)*128;
    #pragma unroll
    for (int n=0;n<8;++n){
      float a0 = acc[n][0], a1 = acc[n][1], a2f = acc[n][2], a3 = acc[n][3];
      float s0 = __shfl_xor(a1,1), s1 = __shfl_xor(a0,1);
      float s2 = __shfl_xor(a3,1), s3 = __shfl_xor(a2f,1);
      float c0 = (t&1) ? s0 : a0;
      float c1 = (t&1) ? a1 : s1;
      float c2 = (t&1) ? s2 : a2f;
      float c3 = (t&1) ? a3 : s3;
      float u0 = __shfl_xor(c2,2), u1 = __shfl_xor(c3,2);
      float u2 = __shfl_xor(c0,2), u3 = __shfl_xor(c1,2);
      f32x4 o;
      o[0] = (t&2) ? u0 : c0;
      o[1] = (t&2) ? u1 : c1;
      o[2] = (t&2) ? c2 : u2;
      o[3] = (t&2) ? c3 : u3;
      float* op = out + rowb + (long)(lg*4 + t)*128 + (li>>2)*4 + n*16;
      __builtin_nontemporal_store(o, (f32x4*)op);
    }
  }
}

// node kernel: R15-passed template; NT final stores (full-sector per instr)
template<int IS_EDGE>
__global__ __launch_bounds__(256, 4)
void encoder_kernel(const float* __restrict__ x, const int* __restrict__ eidx,
                    const float4* __restrict__ xyz,
                    const float* __restrict__ w1, const float* __restrict__ b1,
                    const u16* __restrict__ pw2, const float* __restrict__ b2,
                    const u16* __restrict__ pw3, const float* __restrict__ b3,
                    const float* __restrict__ gw, const float* __restrict__ bw,
                    float* __restrict__ out, long outbase, int nrows, int ntiles)
{
  constexpr int K1  = IS_EDGE ? 4 : 25;
  constexpr int K1P = IS_EDGE ? 4 : 26;
  constexpr int WGS = K1*32 + 4;
  constexpr int SP  = 132;

  __shared__ __align__(16) float w1s[4*WGS];
  __shared__ __align__(16) float b1s[4*36];
  __shared__ __align__(16) float in_s[64*K1P];
  __shared__ __align__(16) unsigned char h12s[16384];
  __shared__ __align__(16) float pts[64*8];
  float* stage = (float*)h12s;

  const int tid  = threadIdx.x;
  const int lane = tid & 63, wave = tid >> 6;
  const int li = lane & 15, lg = lane >> 4;
  const int wbase = wave * 32;

  bf16x8 W2f[2][4], W3f[2][4];
  #pragma unroll
  for (int mt=0;mt<2;++mt)
    #pragma unroll
    for (int kc=0;kc<4;++kc){
      W2f[mt][kc] = *(const bf16x8*)(pw2 + (((wave*2+mt)*4 + kc)*64 + lane)*8);
      W3f[mt][kc] = *(const bf16x8*)(pw3 + (((wave*2+mt)*4 + kc)*64 + lane)*8);
    }
  f32x4 b2q[2];
  #pragma unroll
  for (int mt=0;mt<2;++mt)
    b2q[mt] = *(const f32x4*)(b2 + wbase + mt*16 + lg*4);
  asm volatile("" ::: "memory");

  for (int i = tid; i < K1*32; i += 256){
    int k = i >> 5, col = (i & 31) * 4;
    float4 v = ((const float4*)w1)[i];
    *(float4*)(w1s + (col>>5)*WGS + k*32 + (col&31)) = v;
  }
  if (tid < 128) b1s[(tid>>5)*36 + (tid&31)] = b1[tid];

  const f32x4 zv = {0.f,0.f,0.f,0.f};

  for (int tile = blockIdx.x; tile < ntiles; tile += gridDim.x){
    const int row0 = tile * 64;
    for (int i = tid; i < 64*25; i += 256){
      int r = i / 25, k = i - r*25;
      float v = (row0 + r < nrows) ? x[(long)row0*25 + i] : 0.f;
      in_s[r*K1P + k] = v;
    }
    BAR();

    {
      const int r = tid >> 2, jb0 = (tid & 3) << 5;
      #pragma unroll
      for (int p=0;p<2;++p){
        const int jb = jb0 + p*16;
        const int g = jb >> 5, go = jb & 31;
        float a1[16];
        #pragma unroll
        for (int j=0;j<16;++j) a1[j] = b1s[g*36 + go + j];
        for (int k=0;k<K1;++k){
          float xv = in_s[r*K1P + k];
          const float4* wr = (const float4*)(w1s + g*WGS + k*32 + go);
          #pragma unroll
          for (int j4=0;j4<4;++j4){
            float4 wv = wr[j4];
            a1[j4*4+0] = fmaf(xv, wv.x, a1[j4*4+0]);
            a1[j4*4+1] = fmaf(xv, wv.y, a1[j4*4+1]);
            a1[j4*4+2] = fmaf(xv, wv.z, a1[j4*4+2]);
            a1[j4*4+3] = fmaf(xv, wv.w, a1[j4*4+3]);
          }
        }
        #pragma unroll
        for (int q=0;q<2;++q){
          bf16x8 pk;
          #pragma unroll
          for (int t2=0;t2<8;++t2){
            float v = a1[q*8+t2]; v = v > 0.f ? v : 0.f;
            pk[t2] = (short)f2bf(v);
          }
          *(bf16x8*)(h12s + r*256 + ((((jb>>3)+q) ^ (r&7))<<4)) = pk;
        }
      }
    }
    BAR();

    f32x4 acc[2][4];
    #pragma unroll
    for (int mt=0;mt<2;++mt)
      #pragma unroll
      for (int nt=0;nt<4;++nt) acc[mt][nt] = zv;
    #pragma unroll
    for (int kc=0;kc<4;++kc){
      #pragma unroll
      for (int nt=0;nt<4;++nt){
        bf16x8 hf = *(const bf16x8*)(h12s + (nt*16+li)*256 + (((kc*4+lg)^(li&7))<<4));
        acc[0][nt] = __builtin_amdgcn_mfma_f32_16x16x32_bf16(W2f[0][kc], hf, acc[0][nt], 0,0,0);
        acc[1][nt] = __builtin_amdgcn_mfma_f32_16x16x32_bf16(W2f[1][kc], hf, acc[1][nt], 0,0,0);
      }
    }
    BAR();

    #pragma unroll
    for (int mt=0;mt<2;++mt){
      const int f0 = wbase + mt*16 + lg*4;
      #pragma unroll
      for (int nt=0;nt<4;++nt){
        u16x4 pk;
        #pragma unroll
        for (int j=0;j<4;++j){
          float v = acc[mt][nt][j] + b2q[mt][j];
          v = v > 0.f ? v : 0.f;
          pk[j] = f2bf(v);
        }
        const int r = nt*16 + li;
        *(u16x4*)(h12s + r*256 + (((f0>>3) ^ (r&7))<<4) + ((f0&7)<<1)) = pk;
      }
    }
    BAR();

    #pragma unroll
    for (int mt=0;mt<2;++mt)
      #pragma unroll
      for (int nt=0;nt<4;++nt) acc[mt][nt] = zv;
    #pragma unroll
    for (int kc=0;kc<4;++kc){
      #pragma unroll
      for (int nt=0;nt<4;++nt){
        bf16x8 hf = *(const bf16x8*)(h12s + (nt*16+li)*256 + (((kc*4+lg)^(li&7))<<4));
        acc[0][nt] = __builtin_amdgcn_mfma_f32_16x16x32_bf16(W3f[0][kc], hf, acc[0][nt], 0,0,0);
        acc[1][nt] = __builtin_amdgcn_mfma_f32_16x16x32_bf16(W3f[1][kc], hf, acc[1][nt], 0,0,0);
      }
    }

    f32x4 b3q[2], gq[2], bq[2];
    #pragma unroll
    for (int mt=0;mt<2;++mt){
      b3q[mt] = *(const f32x4*)(b3 + wbase + mt*16 + lg*4);
      gq[mt]  = *(const f32x4*)(gw + wbase + mt*16 + lg*4);
      bq[mt]  = *(const f32x4*)(bw + wbase + mt*16 + lg*4);
    }

    float sA[4]  = {0.f,0.f,0.f,0.f};
    float sqA[4] = {0.f,0.f,0.f,0.f};
    #pragma unroll
    for (int mt=0;mt<2;++mt)
      #pragma unroll
      for (int nt=0;nt<4;++nt)
        #pragma unroll
        for (int j=0;j<4;++j){
          float v = acc[mt][nt][j] + b3q[mt][j];
          acc[mt][nt][j] = v;
          sA[nt] += v; sqA[nt] += v*v;
        }
    #pragma unroll
    for (int nt=0;nt<4;++nt){
      sA[nt]  += __shfl_xor(sA[nt], 16);  sA[nt]  += __shfl_xor(sA[nt], 32);
      sqA[nt] += __shfl_xor(sqA[nt], 16); sqA[nt] += __shfl_xor(sqA[nt], 32);
    }
    if (lg == 0){
      #pragma unroll
      for (int nt=0;nt<4;++nt){
        pts[(nt*16+li)*8 + wave*2]     = sA[nt];
        pts[(nt*16+li)*8 + wave*2 + 1] = sqA[nt];
      }
    }
    BAR();

    #pragma unroll
    for (int nt=0;nt<4;++nt){
      {
        const int r = nt*16 + li;
        f32x4 p0 = *(const f32x4*)(pts + r*8);
        f32x4 p1 = *(const f32x4*)(pts + r*8 + 4);
        float S  = p0[0]+p0[2]+p1[0]+p1[2];
        float SQ = p0[1]+p0[3]+p1[1]+p1[3];
        float mu = S * 0.0078125f;
        float rsv = rsqrtf(SQ*0.0078125f - mu*mu + 1e-5f);
        #pragma unroll
        for (int mt=0;mt<2;++mt){
          f32x4 o;
          #pragma unroll
          for (int j=0;j<4;++j)
            o[j] = (acc[mt][nt][j]-mu)*rsv*gq[mt][j] + bq[mt][j];
          *(f32x4*)(stage + li*SP + wbase + mt*16 + lg*4) = o;
        }
      }
      BAR();
      #pragma unroll
      for (int i=0;i<2;++i){
        const int r = i*8 + (tid>>5);
        const int c = (tid&31)*4;
        const int grow = row0 + nt*16 + r;
        f32x4 v = *(const f32x4*)(stage + r*SP + c);
        if (grow < nrows)
          __builtin_nontemporal_store(v, (f32x4*)(out + outbase + (long)grow*128 + c));
      }
      if (nt < 3) BAR();
    }
  }
}

extern "C" void kernel_launch(void* const* d_in, const int* in_sizes, int n_in,
                              void* d_out, int out_size, void* d_ws, size_t ws_size,
                              hipStream_t stream){
  const float* x   = (const float*)d_in[0];
  const int*  eidx = (const int*)d_in[1];
  const float* ew1 = (const float*)d_in[2];
  const float* eb1 = (const float*)d_in[3];
  const float* ew2 = (const float*)d_in[4];
  const float* eb2 = (const float*)d_in[5];
  const float* ew3 = (const float*)d_in[6];
  const float* eb3 = (const float*)d_in[7];
  const float* eg  = (const float*)d_in[8];
  const float* ebt = (const float*)d_in[9];
  const float* nw1 = (const float*)d_in[10];
  const float* nb1 = (const float*)d_in[11];
  const float* nw2 = (const float*)d_in[12];
  const float* nb2 = (const float*)d_in[13];
  const float* nw3 = (const float*)d_in[14];
  const float* nb3 = (const float*)d_in[15];
  const float* ng  = (const float*)d_in[16];
  const float* nbt = (const float*)d_in[17];
  float* out = (float*)d_out;

  u16* pew2 = (u16*)d_ws;
  u16* pew3 = pew2 + 16384;
  u16* pnw2 = pew3 + 16384;
  u16* pnw3 = pnw2 + 16384;
  float4* xyz = (float4*)((char*)d_ws + 131072);   // 100000 * 16B = 1.6 MB

  pack4<<<32, 256, 0, stream>>>(ew2, ew3, nw2, nw3, pew2, pew3, pnw2, pnw3);
  pack_xyz<<<(N_NODES_ + 255)/256, 256, 0, stream>>>(x, xyz, N_NODES_);
  edge_kernel<<<256, 1024, 0, stream>>>(eidx, xyz, ew1, eb1, pew2, eb2, pew3, eb3,
      eg, ebt, out, (long)N_NODES_ * 128);
  encoder_kernel<0><<<1024, 256, 0, stream>>>(x, nullptr, nullptr, nw1, nb1, pnw2, nb2, pnw3, nb3,
      ng, nbt, out, 0, N_NODES_, (N_NODES_ + 63)/64);
}

// Round 20
// 499.041 us; speedup vs baseline: 1.1322x; 1.1322x over previous
//
#include <hip/hip_runtime.h>

#define E_EDGES 1600000
#define N_NODES_ 100000

typedef unsigned short u16;
typedef unsigned int u32;
typedef short bf16x8 __attribute__((ext_vector_type(8)));
typedef u16 u16x4 __attribute__((ext_vector_type(4)));
typedef float f32x4 __attribute__((ext_vector_type(4)));

#define BAR() do{ asm volatile("s_waitcnt lgkmcnt(0)" ::: "memory"); \
                  __builtin_amdgcn_s_barrier(); }while(0)

__device__ __forceinline__ u16 f2bf(float f){
  u32 u = __builtin_bit_cast(u32, f);
  u += 0x7fffu + ((u >> 16) & 1u);   // round-to-nearest-even
  return (u16)(u >> 16);
}

// Pack 4 (128x128) f32 row-major weight matrices into bf16 fragment order.
// frag (n,kc): lane l holds w[kc*32 + (l>>4)*8 + j][n*16 + (l&15)], j=0..7.
__global__ void pack4(const float* __restrict__ a, const float* __restrict__ b,
                      const float* __restrict__ c, const float* __restrict__ d,
                      u16* __restrict__ pa, u16* __restrict__ pb,
                      u16* __restrict__ pc, u16* __restrict__ pd){
  int tid = blockIdx.x * 256 + threadIdx.x;   // 0..8191
  int mat = tid >> 11, rem = tid & 2047;
  int n = rem >> 8, k = (rem >> 6) & 3, lane = rem & 63;
  const float* w = mat==0 ? a : mat==1 ? b : mat==2 ? c : d;
  u16* p       = mat==0 ? pa : mat==1 ? pb : mat==2 ? pc : pd;
  int rbase = k*32 + (lane>>4)*8;
  int col   = n*16 + (lane&15);
  int o = ((n*4 + k)*64 + lane)*8;
  #pragma unroll
  for (int j=0;j<8;++j) p[o+j] = f2bf(w[(rbase+j)*128 + col]);
}

// Pack xyz (first 3 floats of each 25-float x row) into an L2-friendly float4 table.
__global__ void pack_xyz(const float* __restrict__ x, float4* __restrict__ xyz, int n){
  int i = blockIdx.x * 256 + threadIdx.x;
  if (i < n){
    const float* p = x + (long)i*25;
    float4 v; v.x = p[0]; v.y = p[1]; v.z = p[2]; v.w = 0.f;
    xyz[i] = v;
  }
}

// ============================================================================
// EDGE kernel, wave-independent (R17-proven core): each wave owns a 16-edge
// subtile end-to-end, zero block barriers in the main loop.
// R20 epilogue: NO butterfly, NO nt. After LN, reuse the per-wave 4KB h2
// buffer (dead after a2 reads, ordered by data dependency) as an f32 stage in
// two 8-row halves; copy out with 1KB-contiguous-per-instruction CACHED stores
// (full 128B lines -> no write-allocate fetch, fillBuffer-rate writes).
// R19 counters proved: nt = FETCH 916->340MB but WRITE 1.39x & 2.9TB/s (loss);
// R17 cached partial-line = ~820MB allocate-fetch. Full-line cached = both fixed.
// ============================================================================
__global__ __launch_bounds__(1024, 4)
void edge_kernel(const int* __restrict__ eidx, const float4* __restrict__ xyz,
                 const float* __restrict__ w1, const float* __restrict__ b1,
                 const u16* __restrict__ pw2, const float* __restrict__ b2,
                 const u16* __restrict__ pw3, const float* __restrict__ b3,
                 const float* __restrict__ gw, const float* __restrict__ bw,
                 float* __restrict__ out, long outbase)
{
  __shared__ __align__(16) u16 W2L[16384];            // 32KB fragment bytes
  __shared__ __align__(16) u16 W3L[16384];            // 32KB
  __shared__ __align__(16) float w1s[4*132];          // [k][132] padded row-major
  __shared__ __align__(16) float b1L[128];
  __shared__ __align__(16) unsigned char h2buf[16*4096]; // 4KB per wave (h2, then stage)

  const int tid  = threadIdx.x;
  const int lane = tid & 63, wave = tid >> 6;
  const int li = lane & 15, lg = lane >> 4;
  unsigned char* h2 = h2buf + wave*4096;

  // ---- one-time staging (only block-wide barrier in the kernel) ----
  for (int i = tid; i < 2048; i += 1024){
    ((float4*)W2L)[i] = ((const float4*)pw2)[i];
    ((float4*)W3L)[i] = ((const float4*)pw3)[i];
  }
  for (int i = tid; i < 512; i += 1024){
    int k = i >> 7, f = i & 127;
    w1s[k*132 + f] = w1[i];
  }
  if (tid < 128) b1L[tid] = b1[tid];
  __syncthreads();

  // ---- per-lane constant epilogue params (feature set li + n*16) ----
  float b2v[8], b3v[8], gv[8], bv[8];
  #pragma unroll
  for (int n=0;n<8;++n){
    int f = li + n*16;
    b2v[n] = b2[f]; b3v[n] = b3[f]; gv[n] = gw[f]; bv[n] = bw[f];
  }

  const int NSUB = E_EDGES/16;           // 100000
  const int wid = blockIdx.x*16 + wave;
  const int stride = gridDim.x*16;
  const f32x4 zv = {0.f,0.f,0.f,0.f};

  // prefetch subtile wid (lane handles row li; lg groups redundant -> TA merges)
  float4 pr = {0,0,0,0}, pc = {0,0,0,0};
  if (wid < NSUB){
    long e = (long)wid*16 + li;
    int ir = __builtin_nontemporal_load(eidx + e);
    int ic = __builtin_nontemporal_load(eidx + E_EDGES + e);
    pr = xyz[ir]; pc = xyz[ic];
  }

  for (int s = wid; s < NSUB; s += stride){
    // ---- finish gather math for current subtile ----
    float dx = pr.x-pc.x, dy = pr.y-pc.y, dz = pr.z-pc.z;
    float4 in4; in4.x = dx; in4.y = dy; in4.z = dz;
    in4.w = sqrtf(dx*dx + dy*dy + dz*dz);

    // ---- issue next subtile's gather (overlaps all compute below) ----
    int sn = s + stride;
    if (sn < NSUB){
      long e = (long)sn*16 + li;
      int ir = __builtin_nontemporal_load(eidx + e);
      int ic = __builtin_nontemporal_load(eidx + E_EDGES + e);
      pr = xyz[ir]; pc = xyz[ic];
    }

    // ---- layer 1 -> A-fragments directly (row li, k-chunk lg*8 + kc*32) ----
    bf16x8 af[4];
    #pragma unroll
    for (int kc=0;kc<4;++kc){
      const int f0 = kc*32 + lg*8;
      f32x4 bA = *(const f32x4*)(b1L + f0);
      f32x4 bB = *(const f32x4*)(b1L + f0 + 4);
      float h[8];
      #pragma unroll
      for (int j=0;j<4;++j){ h[j] = bA[j]; h[4+j] = bB[j]; }
      #pragma unroll
      for (int k=0;k<4;++k){
        float xv = (k==0)?in4.x:(k==1)?in4.y:(k==2)?in4.z:in4.w;
        f32x4 wa = *(const f32x4*)(w1s + k*132 + f0);
        f32x4 wb = *(const f32x4*)(w1s + k*132 + f0 + 4);
        #pragma unroll
        for (int j=0;j<4;++j){
          h[j]   = fmaf(xv, wa[j], h[j]);
          h[4+j] = fmaf(xv, wb[j], h[4+j]);
        }
      }
      #pragma unroll
      for (int j=0;j<8;++j){
        float v = h[j] > 0.f ? h[j] : 0.f;
        af[kc][j] = (short)f2bf(v);
      }
    }

    // ---- layer 2: acc[n] = h1 x W2 (B-frags from LDS) ----
    f32x4 acc[8];
    #pragma unroll
    for (int n=0;n<8;++n) acc[n] = zv;
    #pragma unroll
    for (int n=0;n<8;++n)
      #pragma unroll
      for (int kc=0;kc<4;++kc){
        bf16x8 bf = *(const bf16x8*)(W2L + ((n*4+kc)*64 + lane)*8);
        acc[n] = __builtin_amdgcn_mfma_f32_16x16x32_bf16(af[kc], bf, acc[n], 0,0,0);
      }

    // ---- h2 = relu(acc+b2) -> per-wave LDS (R12-proven swizzle bijection) ----
    #pragma unroll
    for (int n=0;n<8;++n){
      #pragma unroll
      for (int j=0;j<4;++j){
        float v = acc[n][j] + b2v[n];
        v = v > 0.f ? v : 0.f;
        const int rr = lg*4 + j;
        const int f  = li + n*16;
        *(u16*)(h2 + rr*256 + ((((f>>3)) ^ (rr&7))<<4) + ((f&7)<<1)) = f2bf(v);
      }
    }
    // wave-local fence: all ds_writes retired before the a2 ds_reads
    asm volatile("s_waitcnt lgkmcnt(0)" ::: "memory");
    __builtin_amdgcn_sched_barrier(0);

    // ---- layer 3: A-frags from h2, B-frags from W3L ----
    bf16x8 a2[4];
    #pragma unroll
    for (int kc=0;kc<4;++kc)
      a2[kc] = *(const bf16x8*)(h2 + li*256 + (((kc*4+lg) ^ (li&7))<<4));
    #pragma unroll
    for (int n=0;n<8;++n) acc[n] = zv;
    #pragma unroll
    for (int n=0;n<8;++n)
      #pragma unroll
      for (int kc=0;kc<4;++kc){
        bf16x8 bf = *(const bf16x8*)(W3L + ((n*4+kc)*64 + lane)*8);
        acc[n] = __builtin_amdgcn_mfma_f32_16x16x32_bf16(a2[kc], bf, acc[n], 0,0,0);
      }

    // ---- LayerNorm fully in registers ----
    float sj[4] = {0,0,0,0}, qj[4] = {0,0,0,0};
    #pragma unroll
    for (int n=0;n<8;++n)
      #pragma unroll
      for (int j=0;j<4;++j){
        float v = acc[n][j] + b3v[n];
        acc[n][j] = v;
        sj[j] += v; qj[j] += v*v;
      }
    #pragma unroll
    for (int j=0;j<4;++j){
      sj[j] += __shfl_xor(sj[j],1);  qj[j] += __shfl_xor(qj[j],1);
      sj[j] += __shfl_xor(sj[j],2);  qj[j] += __shfl_xor(qj[j],2);
      sj[j] += __shfl_xor(sj[j],4);  qj[j] += __shfl_xor(qj[j],4);
      sj[j] += __shfl_xor(sj[j],8);  qj[j] += __shfl_xor(qj[j],8);
    }
    float mu[4], rs[4];
    #pragma unroll
    for (int j=0;j<4;++j){
      mu[j] = sj[j] * 0.0078125f;
      rs[j] = rsqrtf(qj[j]*0.0078125f - mu[j]*mu[j] + 1e-5f);
    }
    #pragma unroll
    for (int n=0;n<8;++n)
      #pragma unroll
      for (int j=0;j<4;++j)
        acc[n][j] = (acc[n][j]-mu[j])*rs[j]*gv[n] + bv[n];

    // ---- epilogue: stage (reuse h2, dead after a2 reads) -> full-line stores ----
    // lane holds (row lg*4+j, feat li+n*16). Two 8-row halves; stage pitch 128
    // floats (8*128*4 = 4096B = h2 size). Stage write: 2-way bank alias (free).
    // Copy: 4 instrs x 1KB contiguous (2 rows) = full 128B lines, CACHED.
    {
      float* stg = (float*)h2;
      const long rowb = outbase + (long)(s*16)*128;
      #pragma unroll
      for (int hf=0; hf<2; ++hf){
        if ((lg>>1) == hf){
          const int rloc = (lg&1)*4;
          #pragma unroll
          for (int n=0;n<8;++n)
            #pragma unroll
            for (int j=0;j<4;++j)
              stg[(rloc+j)*128 + li + n*16] = acc[n][j];
        }
        asm volatile("s_waitcnt lgkmcnt(0)" ::: "memory");
        __builtin_amdgcn_sched_barrier(0);
        #pragma unroll
        for (int i=0;i<4;++i){
          const int rloc = i*2 + (lane>>5);      // 0..7 within half
          const int c = (lane&31)*4;             // float col 0..124
          f32x4 v = *(const f32x4*)(stg + rloc*128 + c);
          *(f32x4*)(out + rowb + (long)(hf*8 + rloc)*128 + c) = v;
        }
        asm volatile("s_waitcnt lgkmcnt(0)" ::: "memory");  // LDS reads done before next stage
        __builtin_amdgcn_sched_barrier(0);
      }
    }
  }
}

// node kernel: R15-passed template, plain cached full-line stores
template<int IS_EDGE>
__global__ __launch_bounds__(256, 4)
void encoder_kernel(const float* __restrict__ x, const int* __restrict__ eidx,
                    const float4* __restrict__ xyz,
                    const float* __restrict__ w1, const float* __restrict__ b1,
                    const u16* __restrict__ pw2, const float* __restrict__ b2,
                    const u16* __restrict__ pw3, const float* __restrict__ b3,
                    const float* __restrict__ gw, const float* __restrict__ bw,
                    float* __restrict__ out, long outbase, int nrows, int ntiles)
{
  constexpr int K1  = IS_EDGE ? 4 : 25;
  constexpr int K1P = IS_EDGE ? 4 : 26;
  constexpr int WGS = K1*32 + 4;
  constexpr int SP  = 132;

  __shared__ __align__(16) float w1s[4*WGS];
  __shared__ __align__(16) float b1s[4*36];
  __shared__ __align__(16) float in_s[64*K1P];
  __shared__ __align__(16) unsigned char h12s[16384];
  __shared__ __align__(16) float pts[64*8];
  float* stage = (float*)h12s;

  const int tid  = threadIdx.x;
  const int lane = tid & 63, wave = tid >> 6;
  const int li = lane & 15, lg = lane >> 4;
  const int wbase = wave * 32;

  bf16x8 W2f[2][4], W3f[2][4];
  #pragma unroll
  for (int mt=0;mt<2;++mt)
    #pragma unroll
    for (int kc=0;kc<4;++kc){
      W2f[mt][kc] = *(const bf16x8*)(pw2 + (((wave*2+mt)*4 + kc)*64 + lane)*8);
      W3f[mt][kc] = *(const bf16x8*)(pw3 + (((wave*2+mt)*4 + kc)*64 + lane)*8);
    }
  f32x4 b2q[2];
  #pragma unroll
  for (int mt=0;mt<2;++mt)
    b2q[mt] = *(const f32x4*)(b2 + wbase + mt*16 + lg*4);
  asm volatile("" ::: "memory");

  for (int i = tid; i < K1*32; i += 256){
    int k = i >> 5, col = (i & 31) * 4;
    float4 v = ((const float4*)w1)[i];
    *(float4*)(w1s + (col>>5)*WGS + k*32 + (col&31)) = v;
  }
  if (tid < 128) b1s[(tid>>5)*36 + (tid&31)] = b1[tid];

  const f32x4 zv = {0.f,0.f,0.f,0.f};

  for (int tile = blockIdx.x; tile < ntiles; tile += gridDim.x){
    const int row0 = tile * 64;
    for (int i = tid; i < 64*25; i += 256){
      int r = i / 25, k = i - r*25;
      float v = (row0 + r < nrows) ? x[(long)row0*25 + i] : 0.f;
      in_s[r*K1P + k] = v;
    }
    BAR();

    {
      const int r = tid >> 2, jb0 = (tid & 3) << 5;
      #pragma unroll
      for (int p=0;p<2;++p){
        const int jb = jb0 + p*16;
        const int g = jb >> 5, go = jb & 31;
        float a1[16];
        #pragma unroll
        for (int j=0;j<16;++j) a1[j] = b1s[g*36 + go + j];
        for (int k=0;k<K1;++k){
          float xv = in_s[r*K1P + k];
          const float4* wr = (const float4*)(w1s + g*WGS + k*32 + go);
          #pragma unroll
          for (int j4=0;j4<4;++j4){
            float4 wv = wr[j4];
            a1[j4*4+0] = fmaf(xv, wv.x, a1[j4*4+0]);
            a1[j4*4+1] = fmaf(xv, wv.y, a1[j4*4+1]);
            a1[j4*4+2] = fmaf(xv, wv.z, a1[j4*4+2]);
            a1[j4*4+3] = fmaf(xv, wv.w, a1[j4*4+3]);
          }
        }
        #pragma unroll
        for (int q=0;q<2;++q){
          bf16x8 pk;
          #pragma unroll
          for (int t2=0;t2<8;++t2){
            float v = a1[q*8+t2]; v = v > 0.f ? v : 0.f;
            pk[t2] = (short)f2bf(v);
          }
          *(bf16x8*)(h12s + r*256 + ((((jb>>3)+q) ^ (r&7))<<4)) = pk;
        }
      }
    }
    BAR();

    f32x4 acc[2][4];
    #pragma unroll
    for (int mt=0;mt<2;++mt)
      #pragma unroll
      for (int nt=0;nt<4;++nt) acc[mt][nt] = zv;
    #pragma unroll
    for (int kc=0;kc<4;++kc){
      #pragma unroll
      for (int nt=0;nt<4;++nt){
        bf16x8 hf = *(const bf16x8*)(h12s + (nt*16+li)*256 + (((kc*4+lg)^(li&7))<<4));
        acc[0][nt] = __builtin_amdgcn_mfma_f32_16x16x32_bf16(W2f[0][kc], hf, acc[0][nt], 0,0,0);
        acc[1][nt] = __builtin_amdgcn_mfma_f32_16x16x32_bf16(W2f[1][kc], hf, acc[1][nt], 0,0,0);
      }
    }
    BAR();

    #pragma unroll
    for (int mt=0;mt<2;++mt){
      const int f0 = wbase + mt*16 + lg*4;
      #pragma unroll
      for (int nt=0;nt<4;++nt){
        u16x4 pk;
        #pragma unroll
        for (int j=0;j<4;++j){
          float v = acc[mt][nt][j] + b2q[mt][j];
          v = v > 0.f ? v : 0.f;
          pk[j] = f2bf(v);
        }
        const int r = nt*16 + li;
        *(u16x4*)(h12s + r*256 + (((f0>>3) ^ (r&7))<<4) + ((f0&7)<<1)) = pk;
      }
    }
    BAR();

    #pragma unroll
    for (int mt=0;mt<2;++mt)
      #pragma unroll
      for (int nt=0;nt<4;++nt) acc[mt][nt] = zv;
    #pragma unroll
    for (int kc=0;kc<4;++kc){
      #pragma unroll
      for (int nt=0;nt<4;++nt){
        bf16x8 hf = *(const bf16x8*)(h12s + (nt*16+li)*256 + (((kc*4+lg)^(li&7))<<4));
        acc[0][nt] = __builtin_amdgcn_mfma_f32_16x16x32_bf16(W3f[0][kc], hf, acc[0][nt], 0,0,0);
        acc[1][nt] = __builtin_amdgcn_mfma_f32_16x16x32_bf16(W3f[1][kc], hf, acc[1][nt], 0,0,0);
      }
    }

    f32x4 b3q[2], gq[2], bq[2];
    #pragma unroll
    for (int mt=0;mt<2;++mt){
      b3q[mt] = *(const f32x4*)(b3 + wbase + mt*16 + lg*4);
      gq[mt]  = *(const f32x4*)(gw + wbase + mt*16 + lg*4);
      bq[mt]  = *(const f32x4*)(bw + wbase + mt*16 + lg*4);
    }

    float sA[4]  = {0.f,0.f,0.f,0.f};
    float sqA[4] = {0.f,0.f,0.f,0.f};
    #pragma unroll
    for (int mt=0;mt<2;++mt)
      #pragma unroll
      for (int nt=0;nt<4;++nt)
        #pragma unroll
        for (int j=0;j<4;++j){
          float v = acc[mt][nt][j] + b3q[mt][j];
          acc[mt][nt][j] = v;
          sA[nt] += v; sqA[nt] += v*v;
        }
    #pragma unroll
    for (int nt=0;nt<4;++nt){
      sA[nt]  += __shfl_xor(sA[nt], 16);  sA[nt]  += __shfl_xor(sA[nt], 32);
      sqA[nt] += __shfl_xor(sqA[nt], 16); sqA[nt] += __shfl_xor(sqA[nt], 32);
    }
    if (lg == 0){
      #pragma unroll
      for (int nt=0;nt<4;++nt){
        pts[(nt*16+li)*8 + wave*2]     = sA[nt];
        pts[(nt*16+li)*8 + wave*2 + 1] = sqA[nt];
      }
    }
    BAR();

    #pragma unroll
    for (int nt=0;nt<4;++nt){
      {
        const int r = nt*16 + li;
        f32x4 p0 = *(const f32x4*)(pts + r*8);
        f32x4 p1 = *(const f32x4*)(pts + r*8 + 4);
        float S  = p0[0]+p0[2]+p1[0]+p1[2];
        float SQ = p0[1]+p0[3]+p1[1]+p1[3];
        float mu = S * 0.0078125f;
        float rsv = rsqrtf(SQ*0.0078125f - mu*mu + 1e-5f);
        #pragma unroll
        for (int mt=0;mt<2;++mt){
          f32x4 o;
          #pragma unroll
          for (int j=0;j<4;++j)
            o[j] = (acc[mt][nt][j]-mu)*rsv*gq[mt][j] + bq[mt][j];
          *(f32x4*)(stage + li*SP + wbase + mt*16 + lg*4) = o;
        }
      }
      BAR();
      #pragma unroll
      for (int i=0;i<2;++i){
        const int r = i*8 + (tid>>5);
        const int c = (tid&31)*4;
        const int grow = row0 + nt*16 + r;
        f32x4 v = *(const f32x4*)(stage + r*SP + c);
        if (grow < nrows)
          *(f32x4*)(out + outbase + (long)grow*128 + c) = v;
      }
      if (nt < 3) BAR();
    }
  }
}

extern "C" void kernel_launch(void* const* d_in, const int* in_sizes, int n_in,
                              void* d_out, int out_size, void* d_ws, size_t ws_size,
                              hipStream_t stream){
  const float* x   = (const float*)d_in[0];
  const int*  eidx = (const int*)d_in[1];
  const float* ew1 = (const float*)d_in[2];
  const float* eb1 = (const float*)d_in[3];
  const float* ew2 = (const float*)d_in[4];
  const float* eb2 = (const float*)d_in[5];
  const float* ew3 = (const float*)d_in[6];
  const float* eb3 = (const float*)d_in[7];
  const float* eg  = (const float*)d_in[8];
  const float* ebt = (const float*)d_in[9];
  const float* nw1 = (const float*)d_in[10];
  const float* nb1 = (const float*)d_in[11];
  const float* nw2 = (const float*)d_in[12];
  const float* nb2 = (const float*)d_in[13];
  const float* nw3 = (const float*)d_in[14];
  const float* nb3 = (const float*)d_in[15];
  const float* ng  = (const float*)d_in[16];
  const float* nbt = (const float*)d_in[17];
  float* out = (float*)d_out;

  u16* pew2 = (u16*)d_ws;
  u16* pew3 = pew2 + 16384;
  u16* pnw2 = pew3 + 16384;
  u16* pnw3 = pnw2 + 16384;
  float4* xyz = (float4*)((char*)d_ws + 131072);   // 100000 * 16B = 1.6 MB

  pack4<<<32, 256, 0, stream>>>(ew2, ew3, nw2, nw3, pew2, pew3, pnw2, pnw3);
  pack_xyz<<<(N_NODES_ + 255)/256, 256, 0, stream>>>(x, xyz, N_NODES_);
  edge_kernel<<<256, 1024, 0, stream>>>(eidx, xyz, ew1, eb1, pew2, eb2, pew3, eb3,
      eg, ebt, out, (long)N_NODES_ * 128);
  encoder_kernel<0><<<1024, 256, 0, stream>>>(x, nullptr, nullptr, nw1, nb1, pnw2, nb2, pnw3, nb3,
      ng, nbt, out, 0, N_NODES_, (N_NODES_ + 63)/64);
}

// Round 21
// 477.768 us; speedup vs baseline: 1.1826x; 1.0445x over previous
//
#include <hip/hip_runtime.h>
#include <hip/hip_bf16.h>

#define E_EDGES 1600000
#define N_NODES_ 100000

typedef unsigned short u16;
typedef unsigned int u32;
typedef short bf16x8 __attribute__((ext_vector_type(8)));
typedef u16 u16x4 __attribute__((ext_vector_type(4)));
typedef float f32x4 __attribute__((ext_vector_type(4)));

#define BAR() do{ asm volatile("s_waitcnt lgkmcnt(0)" ::: "memory"); \
                  __builtin_amdgcn_s_barrier(); }while(0)

// native RNE f32->bf16 (compiler emits v_cvt_pk_bf16_f32; ~1 op vs 4 for manual)
__device__ __forceinline__ u16 f2bf(float f){
  return __builtin_bit_cast(u16, __float2bfloat16(f));
}

// Pack 4 (128x128) f32 row-major weight matrices into bf16 fragment order.
// frag (n,kc): lane l holds w[kc*32 + (l>>4)*8 + j][n*16 + (l&15)], j=0..7.
__global__ void pack4(const float* __restrict__ a, const float* __restrict__ b,
                      const float* __restrict__ c, const float* __restrict__ d,
                      u16* __restrict__ pa, u16* __restrict__ pb,
                      u16* __restrict__ pc, u16* __restrict__ pd){
  int tid = blockIdx.x * 256 + threadIdx.x;   // 0..8191
  int mat = tid >> 11, rem = tid & 2047;
  int n = rem >> 8, k = (rem >> 6) & 3, lane = rem & 63;
  const float* w = mat==0 ? a : mat==1 ? b : mat==2 ? c : d;
  u16* p       = mat==0 ? pa : mat==1 ? pb : mat==2 ? pc : pd;
  int rbase = k*32 + (lane>>4)*8;
  int col   = n*16 + (lane&15);
  int o = ((n*4 + k)*64 + lane)*8;
  #pragma unroll
  for (int j=0;j<8;++j) p[o+j] = f2bf(w[(rbase+j)*128 + col]);
}

// Pack xyz (first 3 floats of each 25-float x row) into an L2-friendly float4 table.
__global__ void pack_xyz(const float* __restrict__ x, float4* __restrict__ xyz, int n){
  int i = blockIdx.x * 256 + threadIdx.x;
  if (i < n){
    const float* p = x + (long)i*25;
    float4 v; v.x = p[0]; v.y = p[1]; v.z = p[2]; v.w = 0.f;
    xyz[i] = v;
  }
}

// ============================================================================
// EDGE kernel = R17 (best, 485us) + native bf16 cvt + exact-division grid.
// Wave-independent: each wave owns a 16-edge subtile end-to-end, zero block
// barriers in the main loop. MFMA non-swapped (R1-proven): A computed directly
// by L1; D: lane holds D[row lg*4+j][col li]. W2/W3 fragments in LDS.
// h2 repack via R12-proven swizzle. Register LN. R17-verified butterfly
// transpose -> 8 adjacent stores/wave cover full 64B sectors (best measured).
// ============================================================================
__global__ __launch_bounds__(1024, 4)
void edge_kernel(const int* __restrict__ eidx, const float4* __restrict__ xyz,
                 const float* __restrict__ w1, const float* __restrict__ b1,
                 const u16* __restrict__ pw2, const float* __restrict__ b2,
                 const u16* __restrict__ pw3, const float* __restrict__ b3,
                 const float* __restrict__ gw, const float* __restrict__ bw,
                 float* __restrict__ out, long outbase)
{
  __shared__ __align__(16) u16 W2L[16384];            // 32KB fragment bytes
  __shared__ __align__(16) u16 W3L[16384];            // 32KB
  __shared__ __align__(16) float w1s[4*132];          // [k][132] padded row-major
  __shared__ __align__(16) float b1L[128];
  __shared__ __align__(16) unsigned char h2buf[16*4096]; // 4KB per wave

  const int tid  = threadIdx.x;
  const int lane = tid & 63, wave = tid >> 6;
  const int li = lane & 15, lg = lane >> 4;
  unsigned char* h2 = h2buf + wave*4096;

  // ---- one-time staging (only block-wide barrier in the kernel) ----
  for (int i = tid; i < 2048; i += 1024){
    ((float4*)W2L)[i] = ((const float4*)pw2)[i];
    ((float4*)W3L)[i] = ((const float4*)pw3)[i];
  }
  for (int i = tid; i < 512; i += 1024){
    int k = i >> 7, f = i & 127;
    w1s[k*132 + f] = w1[i];
  }
  if (tid < 128) b1L[tid] = b1[tid];
  __syncthreads();

  // ---- per-lane constant epilogue params (feature set li + n*16) ----
  float b2v[8], b3v[8], gv[8], bv[8];
  #pragma unroll
  for (int n=0;n<8;++n){
    int f = li + n*16;
    b2v[n] = b2[f]; b3v[n] = b3[f]; gv[n] = gw[f]; bv[n] = bw[f];
  }

  const int NSUB = E_EDGES/16;           // 100000
  const int wid = blockIdx.x*16 + wave;
  const int stride = gridDim.x*16;       // 4000 -> exactly 25 subtiles/wave
  const f32x4 zv = {0.f,0.f,0.f,0.f};

  // prefetch subtile wid
  float4 pr = {0,0,0,0}, pc = {0,0,0,0};
  if (wid < NSUB){
    long e = (long)wid*16 + li;
    int ir = __builtin_nontemporal_load(eidx + e);
    int ic = __builtin_nontemporal_load(eidx + E_EDGES + e);
    pr = xyz[ir]; pc = xyz[ic];
  }

  for (int s = wid; s < NSUB; s += stride){
    // ---- finish gather math for current subtile ----
    float dx = pr.x-pc.x, dy = pr.y-pc.y, dz = pr.z-pc.z;
    float4 in4; in4.x = dx; in4.y = dy; in4.z = dz;
    in4.w = sqrtf(dx*dx + dy*dy + dz*dz);

    // ---- issue next subtile's gather (overlaps all compute below) ----
    int sn = s + stride;
    if (sn < NSUB){
      long e = (long)sn*16 + li;
      int ir = __builtin_nontemporal_load(eidx + e);
      int ic = __builtin_nontemporal_load(eidx + E_EDGES + e);
      pr = xyz[ir]; pc = xyz[ic];
    }

    // ---- layer 1 -> A-fragments directly (row li, k-chunk lg*8 + kc*32) ----
    bf16x8 af[4];
    #pragma unroll
    for (int kc=0;kc<4;++kc){
      const int f0 = kc*32 + lg*8;
      f32x4 bA = *(const f32x4*)(b1L + f0);
      f32x4 bB = *(const f32x4*)(b1L + f0 + 4);
      float h[8];
      #pragma unroll
      for (int j=0;j<4;++j){ h[j] = bA[j]; h[4+j] = bB[j]; }
      #pragma unroll
      for (int k=0;k<4;++k){
        float xv = (k==0)?in4.x:(k==1)?in4.y:(k==2)?in4.z:in4.w;
        f32x4 wa = *(const f32x4*)(w1s + k*132 + f0);
        f32x4 wb = *(const f32x4*)(w1s + k*132 + f0 + 4);
        #pragma unroll
        for (int j=0;j<4;++j){
          h[j]   = fmaf(xv, wa[j], h[j]);
          h[4+j] = fmaf(xv, wb[j], h[4+j]);
        }
      }
      #pragma unroll
      for (int j=0;j<8;++j){
        float v = h[j] > 0.f ? h[j] : 0.f;
        af[kc][j] = (short)f2bf(v);
      }
    }

    // ---- layer 2: acc[n] = h1 x W2 (B-frags from LDS) ----
    f32x4 acc[8];
    #pragma unroll
    for (int n=0;n<8;++n) acc[n] = zv;
    #pragma unroll
    for (int n=0;n<8;++n)
      #pragma unroll
      for (int kc=0;kc<4;++kc){
        bf16x8 bf = *(const bf16x8*)(W2L + ((n*4+kc)*64 + lane)*8);
        acc[n] = __builtin_amdgcn_mfma_f32_16x16x32_bf16(af[kc], bf, acc[n], 0,0,0);
      }

    // ---- h2 = relu(acc+b2) -> per-wave LDS (R12-proven swizzle bijection) ----
    #pragma unroll
    for (int n=0;n<8;++n){
      #pragma unroll
      for (int j=0;j<4;++j){
        float v = acc[n][j] + b2v[n];
        v = v > 0.f ? v : 0.f;
        const int rr = lg*4 + j;
        const int f  = li + n*16;
        *(u16*)(h2 + rr*256 + ((((f>>3)) ^ (rr&7))<<4) + ((f&7)<<1)) = f2bf(v);
      }
    }
    // wave-local fence: all ds_writes retired before the a2 ds_reads
    asm volatile("s_waitcnt lgkmcnt(0)" ::: "memory");
    __builtin_amdgcn_sched_barrier(0);

    // ---- layer 3: A-frags from h2, B-frags from W3L ----
    bf16x8 a2[4];
    #pragma unroll
    for (int kc=0;kc<4;++kc)
      a2[kc] = *(const bf16x8*)(h2 + li*256 + (((kc*4+lg) ^ (li&7))<<4));
    #pragma unroll
    for (int n=0;n<8;++n) acc[n] = zv;
    #pragma unroll
    for (int n=0;n<8;++n)
      #pragma unroll
      for (int kc=0;kc<4;++kc){
        bf16x8 bf = *(const bf16x8*)(W3L + ((n*4+kc)*64 + lane)*8);
        acc[n] = __builtin_amdgcn_mfma_f32_16x16x32_bf16(a2[kc], bf, acc[n], 0,0,0);
      }

    // ---- LayerNorm fully in registers ----
    float sj[4] = {0,0,0,0}, qj[4] = {0,0,0,0};
    #pragma unroll
    for (int n=0;n<8;++n)
      #pragma unroll
      for (int j=0;j<4;++j){
        float v = acc[n][j] + b3v[n];
        acc[n][j] = v;
        sj[j] += v; qj[j] += v*v;
      }
    #pragma unroll
    for (int j=0;j<4;++j){
      sj[j] += __shfl_xor(sj[j],1);  qj[j] += __shfl_xor(qj[j],1);
      sj[j] += __shfl_xor(sj[j],2);  qj[j] += __shfl_xor(qj[j],2);
      sj[j] += __shfl_xor(sj[j],4);  qj[j] += __shfl_xor(qj[j],4);
      sj[j] += __shfl_xor(sj[j],8);  qj[j] += __shfl_xor(qj[j],8);
    }
    float mu[4], rs[4];
    #pragma unroll
    for (int j=0;j<4;++j){
      mu[j] = sj[j] * 0.0078125f;
      rs[j] = rsqrtf(qj[j]*0.0078125f - mu[j]*mu[j] + 1e-5f);
    }
    #pragma unroll
    for (int n=0;n<8;++n)
      #pragma unroll
      for (int j=0;j<4;++j)
        acc[n][j] = (acc[n][j]-mu[j])*rs[j]*gv[n] + bv[n];

    // ---- 4x4 butterfly transpose (R17-verified selectors) + direct stores ----
    const int t = li & 3;
    const long rowb = outbase + (long)(s*16)*128;
    #pragma unroll
    for (int n=0;n<8;++n){
      float a0 = acc[n][0], a1 = acc[n][1], a2f = acc[n][2], a3 = acc[n][3];
      float s0 = __shfl_xor(a1,1), s1 = __shfl_xor(a0,1);
      float s2 = __shfl_xor(a3,1), s3 = __shfl_xor(a2f,1);
      float c0 = (t&1) ? s0 : a0;
      float c1 = (t&1) ? a1 : s1;
      float c2 = (t&1) ? s2 : a2f;
      float c3 = (t&1) ? a3 : s3;
      float u0 = __shfl_xor(c2,2), u1 = __shfl_xor(c3,2);
      float u2 = __shfl_xor(c0,2), u3 = __shfl_xor(c1,2);
      float4 o;
      o.x = (t&2) ? u0 : c0;
      o.y = (t&2) ? u1 : c1;
      o.z = (t&2) ? c2 : u2;
      o.w = (t&2) ? c3 : u3;
      float* op = out + rowb + (long)(lg*4 + t)*128 + (li>>2)*4 + n*16;
      *(float4*)op = o;
    }
  }
}

// node kernel: R15/R20-passed template, cached full-line stores
template<int IS_EDGE>
__global__ __launch_bounds__(256, 4)
void encoder_kernel(const float* __restrict__ x, const int* __restrict__ eidx,
                    const float4* __restrict__ xyz,
                    const float* __restrict__ w1, const float* __restrict__ b1,
                    const u16* __restrict__ pw2, const float* __restrict__ b2,
                    const u16* __restrict__ pw3, const float* __restrict__ b3,
                    const float* __restrict__ gw, const float* __restrict__ bw,
                    float* __restrict__ out, long outbase, int nrows, int ntiles)
{
  constexpr int K1  = IS_EDGE ? 4 : 25;
  constexpr int K1P = IS_EDGE ? 4 : 26;
  constexpr int WGS = K1*32 + 4;
  constexpr int SP  = 132;

  __shared__ __align__(16) float w1s[4*WGS];
  __shared__ __align__(16) float b1s[4*36];
  __shared__ __align__(16) float in_s[64*K1P];
  __shared__ __align__(16) unsigned char h12s[16384];
  __shared__ __align__(16) float pts[64*8];
  float* stage = (float*)h12s;

  const int tid  = threadIdx.x;
  const int lane = tid & 63, wave = tid >> 6;
  const int li = lane & 15, lg = lane >> 4;
  const int wbase = wave * 32;

  bf16x8 W2f[2][4], W3f[2][4];
  #pragma unroll
  for (int mt=0;mt<2;++mt)
    #pragma unroll
    for (int kc=0;kc<4;++kc){
      W2f[mt][kc] = *(const bf16x8*)(pw2 + (((wave*2+mt)*4 + kc)*64 + lane)*8);
      W3f[mt][kc] = *(const bf16x8*)(pw3 + (((wave*2+mt)*4 + kc)*64 + lane)*8);
    }
  f32x4 b2q[2];
  #pragma unroll
  for (int mt=0;mt<2;++mt)
    b2q[mt] = *(const f32x4*)(b2 + wbase + mt*16 + lg*4);
  asm volatile("" ::: "memory");

  for (int i = tid; i < K1*32; i += 256){
    int k = i >> 5, col = (i & 31) * 4;
    float4 v = ((const float4*)w1)[i];
    *(float4*)(w1s + (col>>5)*WGS + k*32 + (col&31)) = v;
  }
  if (tid < 128) b1s[(tid>>5)*36 + (tid&31)] = b1[tid];

  const f32x4 zv = {0.f,0.f,0.f,0.f};

  for (int tile = blockIdx.x; tile < ntiles; tile += gridDim.x){
    const int row0 = tile * 64;
    for (int i = tid; i < 64*25; i += 256){
      int r = i / 25, k = i - r*25;
      float v = (row0 + r < nrows) ? x[(long)row0*25 + i] : 0.f;
      in_s[r*K1P + k] = v;
    }
    BAR();

    {
      const int r = tid >> 2, jb0 = (tid & 3) << 5;
      #pragma unroll
      for (int p=0;p<2;++p){
        const int jb = jb0 + p*16;
        const int g = jb >> 5, go = jb & 31;
        float a1[16];
        #pragma unroll
        for (int j=0;j<16;++j) a1[j] = b1s[g*36 + go + j];
        for (int k=0;k<K1;++k){
          float xv = in_s[r*K1P + k];
          const float4* wr = (const float4*)(w1s + g*WGS + k*32 + go);
          #pragma unroll
          for (int j4=0;j4<4;++j4){
            float4 wv = wr[j4];
            a1[j4*4+0] = fmaf(xv, wv.x, a1[j4*4+0]);
            a1[j4*4+1] = fmaf(xv, wv.y, a1[j4*4+1]);
            a1[j4*4+2] = fmaf(xv, wv.z, a1[j4*4+2]);
            a1[j4*4+3] = fmaf(xv, wv.w, a1[j4*4+3]);
          }
        }
        #pragma unroll
        for (int q=0;q<2;++q){
          bf16x8 pk;
          #pragma unroll
          for (int t2=0;t2<8;++t2){
            float v = a1[q*8+t2]; v = v > 0.f ? v : 0.f;
            pk[t2] = (short)f2bf(v);
          }
          *(bf16x8*)(h12s + r*256 + ((((jb>>3)+q) ^ (r&7))<<4)) = pk;
        }
      }
    }
    BAR();

    f32x4 acc[2][4];
    #pragma unroll
    for (int mt=0;mt<2;++mt)
      #pragma unroll
      for (int nt=0;nt<4;++nt) acc[mt][nt] = zv;
    #pragma unroll
    for (int kc=0;kc<4;++kc){
      #pragma unroll
      for (int nt=0;nt<4;++nt){
        bf16x8 hf = *(const bf16x8*)(h12s + (nt*16+li)*256 + (((kc*4+lg)^(li&7))<<4));
        acc[0][nt] = __builtin_amdgcn_mfma_f32_16x16x32_bf16(W2f[0][kc], hf, acc[0][nt], 0,0,0);
        acc[1][nt] = __builtin_amdgcn_mfma_f32_16x16x32_bf16(W2f[1][kc], hf, acc[1][nt], 0,0,0);
      }
    }
    BAR();

    #pragma unroll
    for (int mt=0;mt<2;++mt){
      const int f0 = wbase + mt*16 + lg*4;
      #pragma unroll
      for (int nt=0;nt<4;++nt){
        u16x4 pk;
        #pragma unroll
        for (int j=0;j<4;++j){
          float v = acc[mt][nt][j] + b2q[mt][j];
          v = v > 0.f ? v : 0.f;
          pk[j] = f2bf(v);
        }
        const int r = nt*16 + li;
        *(u16x4*)(h12s + r*256 + (((f0>>3) ^ (r&7))<<4) + ((f0&7)<<1)) = pk;
      }
    }
    BAR();

    #pragma unroll
    for (int mt=0;mt<2;++mt)
      #pragma unroll
      for (int nt=0;nt<4;++nt) acc[mt][nt] = zv;
    #pragma unroll
    for (int kc=0;kc<4;++kc){
      #pragma unroll
      for (int nt=0;nt<4;++nt){
        bf16x8 hf = *(const bf16x8*)(h12s + (nt*16+li)*256 + (((kc*4+lg)^(li&7))<<4));
        acc[0][nt] = __builtin_amdgcn_mfma_f32_16x16x32_bf16(W3f[0][kc], hf, acc[0][nt], 0,0,0);
        acc[1][nt] = __builtin_amdgcn_mfma_f32_16x16x32_bf16(W3f[1][kc], hf, acc[1][nt], 0,0,0);
      }
    }

    f32x4 b3q[2], gq[2], bq[2];
    #pragma unroll
    for (int mt=0;mt<2;++mt){
      b3q[mt] = *(const f32x4*)(b3 + wbase + mt*16 + lg*4);
      gq[mt]  = *(const f32x4*)(gw + wbase + mt*16 + lg*4);
      bq[mt]  = *(const f32x4*)(bw + wbase + mt*16 + lg*4);
    }

    float sA[4]  = {0.f,0.f,0.f,0.f};
    float sqA[4] = {0.f,0.f,0.f,0.f};
    #pragma unroll
    for (int mt=0;mt<2;++mt)
      #pragma unroll
      for (int nt=0;nt<4;++nt)
        #pragma unroll
        for (int j=0;j<4;++j){
          float v = acc[mt][nt][j] + b3q[mt][j];
          acc[mt][nt][j] = v;
          sA[nt] += v; sqA[nt] += v*v;
        }
    #pragma unroll
    for (int nt=0;nt<4;++nt){
      sA[nt]  += __shfl_xor(sA[nt], 16);  sA[nt]  += __shfl_xor(sA[nt], 32);
      sqA[nt] += __shfl_xor(sqA[nt], 16); sqA[nt] += __shfl_xor(sqA[nt], 32);
    }
    if (lg == 0){
      #pragma unroll
      for (int nt=0;nt<4;++nt){
        pts[(nt*16+li)*8 + wave*2]     = sA[nt];
        pts[(nt*16+li)*8 + wave*2 + 1] = sqA[nt];
      }
    }
    BAR();

    #pragma unroll
    for (int nt=0;nt<4;++nt){
      {
        const int r = nt*16 + li;
        f32x4 p0 = *(const f32x4*)(pts + r*8);
        f32x4 p1 = *(const f32x4*)(pts + r*8 + 4);
        float S  = p0[0]+p0[2]+p1[0]+p1[2];
        float SQ = p0[1]+p0[3]+p1[1]+p1[3];
        float mu = S * 0.0078125f;
        float rsv = rsqrtf(SQ*0.0078125f - mu*mu + 1e-5f);
        #pragma unroll
        for (int mt=0;mt<2;++mt){
          f32x4 o;
          #pragma unroll
          for (int j=0;j<4;++j)
            o[j] = (acc[mt][nt][j]-mu)*rsv*gq[mt][j] + bq[mt][j];
          *(f32x4*)(stage + li*SP + wbase + mt*16 + lg*4) = o;
        }
      }
      BAR();
      #pragma unroll
      for (int i=0;i<2;++i){
        const int r = i*8 + (tid>>5);
        const int c = (tid&31)*4;
        const int grow = row0 + nt*16 + r;
        f32x4 v = *(const f32x4*)(stage + r*SP + c);
        if (grow < nrows)
          *(f32x4*)(out + outbase + (long)grow*128 + c) = v;
      }
      if (nt < 3) BAR();
    }
  }
}

extern "C" void kernel_launch(void* const* d_in, const int* in_sizes, int n_in,
                              void* d_out, int out_size, void* d_ws, size_t ws_size,
                              hipStream_t stream){
  const float* x   = (const float*)d_in[0];
  const int*  eidx = (const int*)d_in[1];
  const float* ew1 = (const float*)d_in[2];
  const float* eb1 = (const float*)d_in[3];
  const float* ew2 = (const float*)d_in[4];
  const float* eb2 = (const float*)d_in[5];
  const float* ew3 = (const float*)d_in[6];
  const float* eb3 = (const float*)d_in[7];
  const float* eg  = (const float*)d_in[8];
  const float* ebt = (const float*)d_in[9];
  const float* nw1 = (const float*)d_in[10];
  const float* nb1 = (const float*)d_in[11];
  const float* nw2 = (const float*)d_in[12];
  const float* nb2 = (const float*)d_in[13];
  const float* nw3 = (const float*)d_in[14];
  const float* nb3 = (const float*)d_in[15];
  const float* ng  = (const float*)d_in[16];
  const float* nbt = (const float*)d_in[17];
  float* out = (float*)d_out;

  u16* pew2 = (u16*)d_ws;
  u16* pew3 = pew2 + 16384;
  u16* pnw2 = pew3 + 16384;
  u16* pnw3 = pnw2 + 16384;
  float4* xyz = (float4*)((char*)d_ws + 131072);   // 100000 * 16B = 1.6 MB

  pack4<<<32, 256, 0, stream>>>(ew2, ew3, nw2, nw3, pew2, pew3, pnw2, pnw3);
  pack_xyz<<<(N_NODES_ + 255)/256, 256, 0, stream>>>(x, xyz, N_NODES_);
  // 250 blocks x 16 waves = 4000 waves: 100000/4000 = exactly 25 subtiles/wave
  edge_kernel<<<250, 1024, 0, stream>>>(eidx, xyz, ew1, eb1, pew2, eb2, pew3, eb3,
      eg, ebt, out, (long)N_NODES_ * 128);
  encoder_kernel<0><<<1024, 256, 0, stream>>>(x, nullptr, nullptr, nw1, nb1, pnw2, nb2, pnw3, nb3,
      ng, nbt, out, 0, N_NODES_, (N_NODES_ + 63)/64);
}